// Round 5
// baseline (686.609 us; speedup 1.0000x reference)
//
#include <hip/hip_runtime.h>
#include <hip/hip_bf16.h>

#define HWD 188
#define NPX (HWD*HWD)
#define NB 4
#define CIN 512
#define CH 64
#define MBOX 200
#define NMAX 500

// output offsets (floats)
#define HEAD_SZ (NB*12*NPX)
#define HM_OFF  HEAD_SZ
#define TB_OFF  (HM_OFF + NB*3*NPX)
#define IND_OFF (TB_OFF + NB*NMAX*8)
#define MSK_OFF (IND_OFF + NB*NMAX)

typedef short sh8 __attribute__((ext_vector_type(8)));
typedef float f4 __attribute__((ext_vector_type(4)));
typedef unsigned short us4 __attribute__((ext_vector_type(4)));

__device__ __constant__ int d_cum[6]  = {0, 2, 3, 6, 8, 9};
__device__ __constant__ int d_outc[6] = {2, 1, 3, 2, 1, 3};

__device__ __forceinline__ unsigned short bf16_bits(float v) {
  union { __hip_bfloat16 h; unsigned short u; } cv;
  cv.h = __float2bfloat16(v);
  return cv.u;
}

// bijective XCD swizzle (requires grid % 8 == 0): contiguous chunk per XCD
__device__ __forceinline__ int xcd_swz(int bid, int grid) {
  return (bid & 7) * (grid >> 3) + (bid >> 3);
}

// ---------------- weight pre-transform to bf16 MFMA layouts ----------------
// w1b [9tap][16icq][64oc][32icr] <- w_shared [64][512][3][3]
// w2b [6][9][64oc][64ic] <- w1_heads [6][64][64][3][3]
// w3b [6][9][16oc][64ic] <- w2_heads [6][3][64][3][3]  (oc padded 3->16)
__global__ __launch_bounds__(256) void wprep(
    const float* __restrict__ ws_, const float* __restrict__ w1_,
    const float* __restrict__ w2_, unsigned short* __restrict__ w1b,
    unsigned short* __restrict__ w2b, unsigned short* __restrict__ w3b) {
  int e = blockIdx.x * 256 + threadIdx.x;
  const int N1 = 9 * 16 * 64 * 32;  // 294912
  const int N2 = 6 * 9 * 64 * 64;   // 221184
  const int N3 = 6 * 9 * 16 * 64;   // 55296
  if (e < N1) {
    int icr = e & 31; int r1 = e >> 5;
    int oc = r1 & 63; int r2 = r1 >> 6;
    int icq = r2 & 15; int tap = r2 >> 4;
    w1b[e] = bf16_bits(ws_[(oc * 512 + icq * 32 + icr) * 9 + tap]);
  } else if (e < N1 + N2) {
    int f = e - N1;
    int h = f / (9 * 64 * 64); int r = f % (9 * 64 * 64);
    int tap = r / (64 * 64); int r2 = r % (64 * 64);
    int oc = r2 / 64; int ic = r2 % 64;
    w2b[f] = bf16_bits(w1_[((h * 64 + oc) * 64 + ic) * 9 + tap]);
  } else if (e < N1 + N2 + N3) {
    int f = e - N1 - N2;
    int h = f / (9 * 16 * 64); int r = f % (9 * 16 * 64);
    int tap = r / (16 * 64); int r2 = r % (16 * 64);
    int oc = r2 / 64; int ic = r2 % 64;
    float v = (oc < 3) ? w2_[((h * 3 + oc) * 64 + ic) * 9 + tap] : 0.f;
    w3b[f] = bf16_bits(v);
  }
}

// ---------------- conv1: 512->64 MFMA, fused BN+ReLU -> bf16 NHWC ----------------
// 256 threads = 4 waves (2 oc-groups x 2 row-groups). tile 8r x 16c x 64oc.
// grid 1152 (all co-resident). LDS [10r][18c][32ic] x2 dbuf = 23 KB.
// staging: 240 items (1/thread): 8 x f4 loads -> 4 x b128 LDS writes.
#define C1_LDS (10*18*32)
__global__ __launch_bounds__(256, 4) void conv1_mfma(
    const float* __restrict__ sf,           // [B][512][188][188] f32
    const unsigned short* __restrict__ wb,  // [9][16][64][32] bf16
    const float* __restrict__ bnp,          // [4][64]
    unsigned short* __restrict__ outp) {    // NHWC [B][188][188][64] bf16
  __shared__ __align__(16) short s_in[2][C1_LDS];
  const int t = threadIdx.x;
  const int swz = xcd_swz(blockIdx.x, 1152);
  const int b = swz / 288;
  const int tt = swz % 288;
  const int y0 = (tt / 12) * 8, x0 = (tt % 12) * 16;
  const int w = t >> 6, lane = t & 63, ln = lane & 15, kg = lane >> 4;
  const int rg = w & 1, og = w >> 1;

  const bool st_act = (t < 240);
  const int icg = t & 3, cg = (t >> 2) % 6, sr = (t >> 2) / 6;
  const int gy_s = y0 - 1 + sr;
  const int gx0_s = x0 - 4 + cg * 4;
  const bool row_ok = (gy_s >= 0 && gy_s < HWD);
  const bool vec_ok = (gx0_s >= 0 && gx0_s + 3 < HWD);
  const float* sbase = sf + (((long long)b * CIN + icg * 8) * HWD + gy_s) * HWD + gx0_s;

  f4 acc[2][4];
#pragma unroll
  for (int i = 0; i < 2; ++i)
#pragma unroll
    for (int j = 0; j < 4; ++j) acc[i][j] = (f4){0.f, 0.f, 0.f, 0.f};

  f4 st[8];
#pragma unroll
  for (int j = 0; j < 8; ++j) st[j] = (f4){0.f, 0.f, 0.f, 0.f};

  // ---- staged load helper (inlined twice) ----
#define C1_LOAD(IC0)                                                        \
  do {                                                                      \
    if (st_act && row_ok) {                                                 \
      const float* p = sbase + (long long)(IC0) * NPX;                      \
      if (vec_ok) {                                                         \
        _Pragma("unroll")                                                   \
        for (int j = 0; j < 8; ++j)                                         \
          st[j] = *reinterpret_cast<const f4*>(p + (long long)j * NPX);     \
      } else {                                                              \
        _Pragma("unroll")                                                   \
        for (int j = 0; j < 8; ++j) st[j] = (f4){0.f, 0.f, 0.f, 0.f};       \
        _Pragma("unroll")                                                   \
        for (int k = 0; k < 4; ++k) {                                       \
          int gx = gx0_s + k;                                               \
          if (gx >= 0 && gx < HWD) {                                        \
            _Pragma("unroll")                                               \
            for (int j = 0; j < 8; ++j) st[j][k] = p[(long long)j * NPX + k];\
          }                                                                 \
        }                                                                   \
      }                                                                     \
    } else {                                                                \
      _Pragma("unroll")                                                     \
      for (int j = 0; j < 8; ++j) st[j] = (f4){0.f, 0.f, 0.f, 0.f};         \
    }                                                                       \
  } while (0)

#define C1_WRITE(BUF)                                                       \
  do {                                                                      \
    if (st_act) {                                                           \
      _Pragma("unroll")                                                     \
      for (int k = 0; k < 4; ++k) {                                         \
        int col = cg * 4 + k - 3;                                           \
        if ((unsigned)col < 18u) {                                          \
          sh8 pk;                                                           \
          _Pragma("unroll")                                                 \
          for (int j = 0; j < 8; ++j) pk[j] = (short)bf16_bits(st[j][k]);   \
          *reinterpret_cast<sh8*>(&(BUF)[(sr * 18 + col) * 32 + icg * 8]) = pk; \
        }                                                                   \
      }                                                                     \
    }                                                                       \
  } while (0)

  // prologue: stage step 0
  C1_LOAD(0);
  C1_WRITE(s_in[0]);
  __syncthreads();

  for (int s = 0; s < 16; ++s) {
    const short* cur = s_in[s & 1];
    // issue next step's global loads (in flight through MFMA phase)
    if (s < 15) C1_LOAD((s + 1) * 32);
#pragma unroll
    for (int tap = 0; tap < 9; ++tap) {
      const int ky = tap / 3, kx = tap % 3;
      sh8 af[2];
#pragma unroll
      for (int i = 0; i < 2; ++i)
        af[i] = *reinterpret_cast<const sh8*>(
            wb + (((tap * 16 + s) * 64) + (2 * og + i) * 16 + ln) * 32 + kg * 8);
#pragma unroll
      for (int nt = 0; nt < 4; ++nt) {
        const int rr = 4 * rg + nt + ky;
        const int cc = ln + kx;
        sh8 bf = *reinterpret_cast<const sh8*>(&cur[(rr * 18 + cc) * 32 + kg * 8]);
#pragma unroll
        for (int i = 0; i < 2; ++i)
          acc[i][nt] = __builtin_amdgcn_mfma_f32_16x16x32_bf16(
              af[i], bf, acc[i][nt], 0, 0, 0);
      }
    }
    if (s < 15) C1_WRITE(s_in[(s & 1) ^ 1]);
    __syncthreads();
  }

  // epilogue: BN + ReLU -> bf16 NHWC
#pragma unroll
  for (int i = 0; i < 2; ++i) {
    const int ocb = (2 * og + i) * 16 + kg * 4;
    f4 g4 = *reinterpret_cast<const f4*>(bnp + ocb);
    f4 b4 = *reinterpret_cast<const f4*>(bnp + 64 + ocb);
    f4 m4 = *reinterpret_cast<const f4*>(bnp + 128 + ocb);
    f4 v4 = *reinterpret_cast<const f4*>(bnp + 192 + ocb);
    f4 sc, bi;
#pragma unroll
    for (int j = 0; j < 4; ++j) {
      sc[j] = g4[j] * rsqrtf(v4[j] + 1e-5f);
      bi[j] = b4[j] - m4[j] * sc[j];
    }
#pragma unroll
    for (int nt = 0; nt < 4; ++nt) {
      int y = y0 + 4 * rg + nt;
      int x = x0 + ln;
      if (y < HWD && x < HWD) {
        us4 pk;
#pragma unroll
        for (int j = 0; j < 4; ++j)
          pk[j] = bf16_bits(fmaxf(acc[i][nt][j] * sc[j] + bi[j], 0.f));
        *reinterpret_cast<us4*>(outp + (((long long)b * HWD + y) * HWD + x) * 64 + ocb) = pk;
      }
    }
  }
#undef C1_LOAD
#undef C1_WRITE
}

// ---------------- conv2 all-heads: stage shared tile once, loop 6 heads ----------
// 256 thr = 4 row-pair waves. tile 8x32x64oc. LDS [10][34][72] = 49 KB.
__global__ __launch_bounds__(256, 3) void conv2_allheads(
    const unsigned short* __restrict__ inp,   // shared NHWC bf16
    const unsigned short* __restrict__ w2b,   // [6][9][64][64]
    const float* __restrict__ bnH,            // [6][4][64]
    unsigned short* __restrict__ tmp0,        // tmp base
    int h_lo, int h_hi, long long tstride) {
  __shared__ __align__(16) short s_in[10 * 34 * 72];
  const int t = threadIdx.x;
  const int swz = xcd_swz(blockIdx.x, gridDim.x);
  const int b = swz / 144;
  const int tt = swz % 144;
  const int y0 = (tt / 6) * 8, x0 = (tt % 6) * 32;
  const int w = t >> 6, lane = t & 63, ln = lane & 15, kg = lane >> 4;

  for (int idx = t; idx < 2720; idx += 256) {
    int ch = idx & 7; int pix = idx >> 3;
    int c = pix % 34; int r = pix / 34;
    int gy = y0 - 1 + r, gx = x0 - 1 + c;
    sh8 v = (sh8){0, 0, 0, 0, 0, 0, 0, 0};
    if (gy >= 0 && gy < HWD && gx >= 0 && gx < HWD)
      v = *reinterpret_cast<const sh8*>(
          &inp[(((long long)b * HWD + gy) * HWD + gx) * 64 + ch * 8]);
    *reinterpret_cast<sh8*>(&s_in[(r * 34 + c) * 72 + ch * 8]) = v;
  }
  __syncthreads();

  for (int h = h_lo; h < h_hi; ++h) {
    f4 acc[4][4];
#pragma unroll
    for (int i = 0; i < 4; ++i)
#pragma unroll
      for (int j = 0; j < 4; ++j) acc[i][j] = (f4){0.f, 0.f, 0.f, 0.f};
#pragma unroll
    for (int icq = 0; icq < 2; ++icq) {
#pragma unroll
      for (int tap = 0; tap < 9; ++tap) {
        const int ky = tap / 3, kx = tap % 3;
        sh8 af[4];
#pragma unroll
        for (int ot = 0; ot < 4; ++ot)
          af[ot] = *reinterpret_cast<const sh8*>(
              w2b + (((h * 9 + tap) * 64) + ot * 16 + ln) * 64 + icq * 32 + kg * 8);
#pragma unroll
        for (int nt = 0; nt < 4; ++nt) {
          const int rr = 2 * w + (nt >> 1) + ky;
          const int cc = (nt & 1) * 16 + ln + kx;
          sh8 bf = *reinterpret_cast<const sh8*>(
              &s_in[(rr * 34 + cc) * 72 + icq * 32 + kg * 8]);
#pragma unroll
          for (int ot = 0; ot < 4; ++ot)
            acc[ot][nt] = __builtin_amdgcn_mfma_f32_16x16x32_bf16(
                af[ot], bf, acc[ot][nt], 0, 0, 0);
        }
      }
    }
    unsigned short* outp = tmp0 + (long long)h * tstride;
    const float* bnp = bnH + h * 256;
#pragma unroll
    for (int ot = 0; ot < 4; ++ot) {
      const int ocb = ot * 16 + kg * 4;
      f4 g4 = *reinterpret_cast<const f4*>(bnp + ocb);
      f4 b4 = *reinterpret_cast<const f4*>(bnp + 64 + ocb);
      f4 m4 = *reinterpret_cast<const f4*>(bnp + 128 + ocb);
      f4 v4 = *reinterpret_cast<const f4*>(bnp + 192 + ocb);
      f4 sc, bi;
#pragma unroll
      for (int j = 0; j < 4; ++j) {
        sc[j] = g4[j] * rsqrtf(v4[j] + 1e-5f);
        bi[j] = b4[j] - m4[j] * sc[j];
      }
#pragma unroll
      for (int nt = 0; nt < 4; ++nt) {
        int y = y0 + 2 * w + (nt >> 1);
        int x = x0 + (nt & 1) * 16 + ln;
        if (y < HWD && x < HWD) {
          us4 pk;
#pragma unroll
          for (int j = 0; j < 4; ++j)
            pk[j] = bf16_bits(fmaxf(acc[ot][nt][j] * sc[j] + bi[j], 0.f));
          *reinterpret_cast<us4*>(outp + (((long long)b * HWD + y) * HWD + x) * 64 + ocb) = pk;
        }
      }
    }
  }
}

// ---------------- conv3: 64->16(3) + bias -> f32 NCHW head slices ----------------
__global__ __launch_bounds__(256, 3) void conv3_mfma(
    const unsigned short* __restrict__ tmp0,  // tmp base
    const unsigned short* __restrict__ w3b,   // [6][9][16][64]
    const float* __restrict__ b2,             // [6][3]
    float* __restrict__ hout,                 // head_out
    int h_base, long long tstride) {
  __shared__ __align__(16) short s_in[10 * 34 * 72];
  const int t = threadIdx.x;
  const int swz = xcd_swz(blockIdx.x, gridDim.x);
  const int h = h_base + swz / 576;
  const int rem = swz % 576;
  const int b = rem / 144;
  const int tt = rem % 144;
  const int y0 = (tt / 6) * 8, x0 = (tt % 6) * 32;
  const int w = t >> 6, lane = t & 63, ln = lane & 15, kg = lane >> 4;
  const unsigned short* inp = tmp0 + (long long)h * tstride;

  for (int idx = t; idx < 2720; idx += 256) {
    int ch = idx & 7; int pix = idx >> 3;
    int c = pix % 34; int r = pix / 34;
    int gy = y0 - 1 + r, gx = x0 - 1 + c;
    sh8 v = (sh8){0, 0, 0, 0, 0, 0, 0, 0};
    if (gy >= 0 && gy < HWD && gx >= 0 && gx < HWD)
      v = *reinterpret_cast<const sh8*>(
          &inp[(((long long)b * HWD + gy) * HWD + gx) * 64 + ch * 8]);
    *reinterpret_cast<sh8*>(&s_in[(r * 34 + c) * 72 + ch * 8]) = v;
  }
  __syncthreads();

  f4 acc[4];
#pragma unroll
  for (int j = 0; j < 4; ++j) acc[j] = (f4){0.f, 0.f, 0.f, 0.f};
#pragma unroll
  for (int icq = 0; icq < 2; ++icq) {
#pragma unroll
    for (int tap = 0; tap < 9; ++tap) {
      const int ky = tap / 3, kx = tap % 3;
      sh8 af = *reinterpret_cast<const sh8*>(
          w3b + (((h * 9 + tap) * 16) + ln) * 64 + icq * 32 + kg * 8);
#pragma unroll
      for (int nt = 0; nt < 4; ++nt) {
        const int rr = 2 * w + (nt >> 1) + ky;
        const int cc = (nt & 1) * 16 + ln + kx;
        sh8 bf = *reinterpret_cast<const sh8*>(
            &s_in[(rr * 34 + cc) * 72 + icq * 32 + kg * 8]);
        acc[nt] = __builtin_amdgcn_mfma_f32_16x16x32_bf16(af, bf, acc[nt], 0, 0, 0);
      }
    }
  }
  const int c_off = d_cum[h], noc = d_outc[h];
#pragma unroll
  for (int nt = 0; nt < 4; ++nt) {
    int y = y0 + 2 * w + (nt >> 1);
    int x = x0 + (nt & 1) * 16 + ln;
    if (y < HWD && x < HWD) {
#pragma unroll
      for (int j = 0; j < 4; ++j) {
        int oc = kg * 4 + j;
        if (oc < noc)
          hout[((long long)b * 12 + c_off + oc) * NPX + y * HWD + x] =
              acc[nt][j] + b2[h * 3 + oc];
      }
    }
  }
}

// ---------------- assign_targets: per-box ----------------
__global__ __launch_bounds__(256) void targets_kernel(
    const float* __restrict__ gt, float* __restrict__ out, float* __restrict__ boxp) {
  int idx = blockIdx.x * 256 + threadIdx.x;
  if (idx >= NB * NMAX) return;
  int b = idx / NMAX, j = idx - b * NMAX;
  float vals[8] = {0, 0, 0, 0, 0, 0, 0, 0};
  float indf = 0.f, mkf = 0.f;
  if (j < MBOX) {
    const float* g = gt + (b * MBOX + j) * 8;
    float x = g[0], y = g[1], z = g[2], dx = g[3], dy = g[4], dz = g[5];
    float hd = g[6], cls = g[7];
    float cx = (x - (-75.2f)) / 0.1f / 8.0f;
    cx = fminf(fmaxf(cx, 0.0f), (float)HWD - 0.5f);
    float cy = (y - (-75.2f)) / 0.1f / 8.0f;
    cy = fminf(fmaxf(cy, 0.0f), (float)HWD - 0.5f);
    float cxf = floorf(cx), cyf = floorf(cy);
    int cxi = (int)cxf, cyi = (int)cyf;
    float hh = dx / 0.1f / 8.0f;
    float ww = dy / 0.1f / 8.0f;
    const float ov = 0.1f;
    float b1 = hh + ww;
    float c1 = ww * hh * (1.0f - ov) / (1.0f + ov);
    float sq1 = sqrtf(fmaxf(b1 * b1 - 4.0f * c1, 0.0f));
    float r1 = (b1 + sq1) / 2.0f;
    float b2_ = 2.0f * (hh + ww);
    float c2 = (1.0f - ov) * ww * hh;
    float sq2 = sqrtf(fmaxf(b2_ * b2_ - 16.0f * c2, 0.0f));
    float r2 = (b2_ + sq2) / 2.0f;
    float a3 = 4.0f * ov;
    float b3 = -2.0f * ov * (hh + ww);
    float c3 = (ov - 1.0f) * ww * hh;
    float sq3 = sqrtf(fmaxf(b3 * b3 - 4.0f * a3 * c3, 0.0f));
    float r3 = (b3 + sq3) / 2.0f;
    float r = fminf(fminf(r1, r2), r3);
    r = fmaxf(floorf(r), 2.0f);
    float sigma = (2.0f * r + 1.0f) / 6.0f;
    float inv2s2 = 1.0f / (2.0f * sigma * sigma);
    bool valid = (dx > 0.0f) && (dy > 0.0f);
    float vf = valid ? 1.0f : 0.0f;
    vals[0] = (cx - cxf) * vf;
    vals[1] = (cy - cyf) * vf;
    vals[2] = z * vf;
    vals[3] = logf(dx) * vf;
    vals[4] = logf(dy) * vf;
    vals[5] = logf(dz) * vf;
    vals[6] = cosf(hd) * vf;
    vals[7] = sinf(hd) * vf;
    indf = (float)((cyi * HWD + cxi) * (valid ? 1 : 0));
    mkf = vf;
    float* bp = boxp + (b * MBOX + j) * 8;
    bp[0] = cxf; bp[1] = cyf; bp[2] = r; bp[3] = inv2s2;
    bp[4] = valid ? cls : 0.0f; bp[5] = 0.f; bp[6] = 0.f; bp[7] = 0.f;
  }
  float* tb = out + TB_OFF + (b * NMAX + j) * 8;
#pragma unroll
  for (int k = 0; k < 8; ++k) tb[k] = vals[k];
  out[IND_OFF + b * NMAX + j] = indf;
  out[MSK_OFF + b * NMAX + j] = mkf;
}

// ---------------- heatmap: per-pixel max over boxes ----------------
__global__ __launch_bounds__(256) void heatmap_kernel(
    const float* __restrict__ boxp, float* __restrict__ out) {
  __shared__ float s_bp[MBOX][5];
  const int t = threadIdx.x, b = blockIdx.y;
  for (int e = t; e < MBOX * 5; e += 256) {
    int j = e / 5, k = e - j * 5;
    s_bp[j][k] = boxp[(b * MBOX + j) * 8 + k];
  }
  __syncthreads();
  int p = blockIdx.x * 256 + t;
  if (p >= NPX) return;
  int y = p / HWD, x = p - y * HWD;
  float a0 = 0.f, a1 = 0.f, a2 = 0.f;
  for (int j = 0; j < MBOX; ++j) {
    int c = (int)s_bp[j][4];
    if (c == 0) continue;
    float ox = (float)x - s_bp[j][0];
    float oy = (float)y - s_bp[j][1];
    float r = s_bp[j][2];
    if (fabsf(ox) <= r && fabsf(oy) <= r) {
      float gg = expf(-(ox * ox + oy * oy) * s_bp[j][3]);
      if (c == 1) a0 = fmaxf(a0, gg);
      else if (c == 2) a1 = fmaxf(a1, gg);
      else a2 = fmaxf(a2, gg);
    }
  }
  int base = HM_OFF + (b * 3 * HWD + y) * HWD + x;
  out[base] = a0;
  out[base + NPX] = a1;
  out[base + 2 * NPX] = a2;
}

extern "C" void kernel_launch(void* const* d_in, const int* in_sizes, int n_in,
                              void* d_out, int out_size, void* d_ws, size_t ws_size,
                              hipStream_t stream) {
  (void)in_sizes; (void)n_in; (void)out_size;
  const float* sf = (const float*)d_in[0];
  const float* gt = (const float*)d_in[1];
  const float* w_shared = (const float*)d_in[2];
  const float* bn_shared = (const float*)d_in[3];
  const float* w1 = (const float*)d_in[4];
  const float* bnH = (const float*)d_in[5];
  const float* w2 = (const float*)d_in[6];
  const float* b2 = (const float*)d_in[7];
  float* out = (float*)d_out;
  char* ws = (char*)d_ws;

  // ws layout (bytes)
  const size_t SH = (size_t)NB * NPX * 64 * 2;          // 18,096,128
  unsigned short* shared_t = (unsigned short*)ws;
  unsigned short* w1b = (unsigned short*)(ws + SH);                       // 589,824
  unsigned short* w2b = (unsigned short*)(ws + SH + 589824);              // 442,368
  unsigned short* w3b = (unsigned short*)(ws + SH + 589824 + 442368);     // 110,592
  float* boxp = (float*)(ws + SH + 589824 + 442368 + 110592);             // 25,600
  const size_t off_tmp = SH + 589824 + 442368 + 110592 + 25600;           // 19,264,512
  unsigned short* tmp0 = (unsigned short*)(ws + off_tmp);

  const bool wide = ws_size >= off_tmp + 6 * SH;                 // ~128 MB
  const long long tstride = wide ? (long long)(SH / 2) : 0LL;    // shorts

  wprep<<<2232, 256, 0, stream>>>(w_shared, w1, w2, w1b, w2b, w3b);

  conv1_mfma<<<1152, 256, 0, stream>>>(sf, w1b, bn_shared, shared_t);

  if (wide) {
    conv2_allheads<<<576, 256, 0, stream>>>(shared_t, w2b, bnH, tmp0, 0, 6, tstride);
    conv3_mfma<<<3456, 256, 0, stream>>>(tmp0, w3b, b2, out, 0, tstride);
  } else {
    for (int h = 0; h < 6; ++h) {
      conv2_allheads<<<576, 256, 0, stream>>>(shared_t, w2b, bnH, tmp0, h, h + 1, 0);
      conv3_mfma<<<576, 256, 0, stream>>>(tmp0, w3b, b2, out, h, 0);
    }
  }

  targets_kernel<<<(NB * NMAX + 255) / 256, 256, 0, stream>>>(gt, out, boxp);
  heatmap_kernel<<<dim3((NPX + 255) / 256, NB), 256, 0, stream>>>(boxp, out);
}

// Round 6
// 594.822 us; speedup vs baseline: 1.1543x; 1.1543x over previous
//
#include <hip/hip_runtime.h>
#include <hip/hip_bf16.h>

#define HWD 188
#define NPX (HWD*HWD)
#define NB 4
#define CIN 512
#define CH 64
#define MBOX 200
#define NMAX 500

// output offsets (floats)
#define HEAD_SZ (NB*12*NPX)
#define HM_OFF  HEAD_SZ
#define TB_OFF  (HM_OFF + NB*3*NPX)
#define IND_OFF (TB_OFF + NB*NMAX*8)
#define MSK_OFF (IND_OFF + NB*NMAX)

typedef short sh8 __attribute__((ext_vector_type(8)));
typedef float f4 __attribute__((ext_vector_type(4)));
typedef unsigned short us4 __attribute__((ext_vector_type(4)));

__device__ __constant__ int d_cum[6]  = {0, 2, 3, 6, 8, 9};
__device__ __constant__ int d_outc[6] = {2, 1, 3, 2, 1, 3};

__device__ __forceinline__ unsigned short bf16_bits(float v) {
  union { __hip_bfloat16 h; unsigned short u; } cv;
  cv.h = __float2bfloat16(v);
  return cv.u;
}

// bijective XCD swizzle (requires grid % 8 == 0): contiguous chunk per XCD
__device__ __forceinline__ int xcd_swz(int bid, int grid) {
  return (bid & 7) * (grid >> 3) + (bid >> 3);
}

// ---------------- weight pre-transform to bf16 MFMA layouts ----------------
// w1b [9tap][16icq][64oc][32icr] <- w_shared [64][512][3][3]
// w2b [6][9][64oc][64ic] <- w1_heads [6][64][64][3][3]
// w3b [6][9][16oc][64ic] <- w2_heads [6][3][64][3][3]  (oc padded 3->16)
__global__ __launch_bounds__(256) void wprep(
    const float* __restrict__ ws_, const float* __restrict__ w1_,
    const float* __restrict__ w2_, unsigned short* __restrict__ w1b,
    unsigned short* __restrict__ w2b, unsigned short* __restrict__ w3b) {
  int e = blockIdx.x * 256 + threadIdx.x;
  const int N1 = 9 * 16 * 64 * 32;  // 294912
  const int N2 = 6 * 9 * 64 * 64;   // 221184
  const int N3 = 6 * 9 * 16 * 64;   // 55296
  if (e < N1) {
    int icr = e & 31; int r1 = e >> 5;
    int oc = r1 & 63; int r2 = r1 >> 6;
    int icq = r2 & 15; int tap = r2 >> 4;
    w1b[e] = bf16_bits(ws_[(oc * 512 + icq * 32 + icr) * 9 + tap]);
  } else if (e < N1 + N2) {
    int f = e - N1;
    int h = f / (9 * 64 * 64); int r = f % (9 * 64 * 64);
    int tap = r / (64 * 64); int r2 = r % (64 * 64);
    int oc = r2 / 64; int ic = r2 % 64;
    w2b[f] = bf16_bits(w1_[((h * 64 + oc) * 64 + ic) * 9 + tap]);
  } else if (e < N1 + N2 + N3) {
    int f = e - N1 - N2;
    int h = f / (9 * 16 * 64); int r = f % (9 * 16 * 64);
    int tap = r / (16 * 64); int r2 = r % (16 * 64);
    int oc = r2 / 64; int ic = r2 % 64;
    float v = (oc < 3) ? w2_[((h * 3 + oc) * 64 + ic) * 9 + tap] : 0.f;
    w3b[f] = bf16_bits(v);
  }
}

// ---------------- conv1: 512->64 MFMA, fused BN+ReLU -> bf16 NHWC ----------------
// (unchanged from round 4)
#define C1_LDS (10*18*32)
__global__ __launch_bounds__(256, 4) void conv1_mfma(
    const float* __restrict__ sf,           // [B][512][188][188] f32
    const unsigned short* __restrict__ wb,  // [9][16][64][32] bf16
    const float* __restrict__ bnp,          // [4][64]
    unsigned short* __restrict__ outp) {    // NHWC [B][188][188][64] bf16
  __shared__ __align__(16) short s_in[2][C1_LDS];
  const int t = threadIdx.x;
  const int swz = xcd_swz(blockIdx.x, 1152);
  const int b = swz / 288;
  const int tt = swz % 288;
  const int y0 = (tt / 12) * 8, x0 = (tt % 12) * 16;
  const int w = t >> 6, lane = t & 63, ln = lane & 15, kg = lane >> 4;
  const int rg = w & 1, og = w >> 1;

  const bool st_act = (t < 240);
  const int icg = t & 3, cg = (t >> 2) % 6, sr = (t >> 2) / 6;
  const int gy_s = y0 - 1 + sr;
  const int gx0_s = x0 - 4 + cg * 4;
  const bool row_ok = (gy_s >= 0 && gy_s < HWD);
  const bool vec_ok = (gx0_s >= 0 && gx0_s + 3 < HWD);
  const float* sbase = sf + (((long long)b * CIN + icg * 8) * HWD + gy_s) * HWD + gx0_s;

  f4 acc[2][4];
#pragma unroll
  for (int i = 0; i < 2; ++i)
#pragma unroll
    for (int j = 0; j < 4; ++j) acc[i][j] = (f4){0.f, 0.f, 0.f, 0.f};

  f4 st[8];
#pragma unroll
  for (int j = 0; j < 8; ++j) st[j] = (f4){0.f, 0.f, 0.f, 0.f};

#define C1_LOAD(IC0)                                                        \
  do {                                                                      \
    if (st_act && row_ok) {                                                 \
      const float* p = sbase + (long long)(IC0) * NPX;                      \
      if (vec_ok) {                                                         \
        _Pragma("unroll")                                                   \
        for (int j = 0; j < 8; ++j)                                         \
          st[j] = *reinterpret_cast<const f4*>(p + (long long)j * NPX);     \
      } else {                                                              \
        _Pragma("unroll")                                                   \
        for (int j = 0; j < 8; ++j) st[j] = (f4){0.f, 0.f, 0.f, 0.f};       \
        _Pragma("unroll")                                                   \
        for (int k = 0; k < 4; ++k) {                                       \
          int gx = gx0_s + k;                                               \
          if (gx >= 0 && gx < HWD) {                                        \
            _Pragma("unroll")                                               \
            for (int j = 0; j < 8; ++j) st[j][k] = p[(long long)j * NPX + k];\
          }                                                                 \
        }                                                                   \
      }                                                                     \
    } else {                                                                \
      _Pragma("unroll")                                                     \
      for (int j = 0; j < 8; ++j) st[j] = (f4){0.f, 0.f, 0.f, 0.f};         \
    }                                                                       \
  } while (0)

#define C1_WRITE(BUF)                                                       \
  do {                                                                      \
    if (st_act) {                                                           \
      _Pragma("unroll")                                                     \
      for (int k = 0; k < 4; ++k) {                                         \
        int col = cg * 4 + k - 3;                                           \
        if ((unsigned)col < 18u) {                                          \
          sh8 pk;                                                           \
          _Pragma("unroll")                                                 \
          for (int j = 0; j < 8; ++j) pk[j] = (short)bf16_bits(st[j][k]);   \
          *reinterpret_cast<sh8*>(&(BUF)[(sr * 18 + col) * 32 + icg * 8]) = pk; \
        }                                                                   \
      }                                                                     \
    }                                                                       \
  } while (0)

  C1_LOAD(0);
  C1_WRITE(s_in[0]);
  __syncthreads();

  for (int s = 0; s < 16; ++s) {
    const short* cur = s_in[s & 1];
    if (s < 15) C1_LOAD((s + 1) * 32);
#pragma unroll
    for (int tap = 0; tap < 9; ++tap) {
      const int ky = tap / 3, kx = tap % 3;
      sh8 af[2];
#pragma unroll
      for (int i = 0; i < 2; ++i)
        af[i] = *reinterpret_cast<const sh8*>(
            wb + (((tap * 16 + s) * 64) + (2 * og + i) * 16 + ln) * 32 + kg * 8);
#pragma unroll
      for (int nt = 0; nt < 4; ++nt) {
        const int rr = 4 * rg + nt + ky;
        const int cc = ln + kx;
        sh8 bf = *reinterpret_cast<const sh8*>(&cur[(rr * 18 + cc) * 32 + kg * 8]);
#pragma unroll
        for (int i = 0; i < 2; ++i)
          acc[i][nt] = __builtin_amdgcn_mfma_f32_16x16x32_bf16(
              af[i], bf, acc[i][nt], 0, 0, 0);
      }
    }
    if (s < 15) C1_WRITE(s_in[(s & 1) ^ 1]);
    __syncthreads();
  }

#pragma unroll
  for (int i = 0; i < 2; ++i) {
    const int ocb = (2 * og + i) * 16 + kg * 4;
    f4 g4 = *reinterpret_cast<const f4*>(bnp + ocb);
    f4 b4 = *reinterpret_cast<const f4*>(bnp + 64 + ocb);
    f4 m4 = *reinterpret_cast<const f4*>(bnp + 128 + ocb);
    f4 v4 = *reinterpret_cast<const f4*>(bnp + 192 + ocb);
    f4 sc, bi;
#pragma unroll
    for (int j = 0; j < 4; ++j) {
      sc[j] = g4[j] * rsqrtf(v4[j] + 1e-5f);
      bi[j] = b4[j] - m4[j] * sc[j];
    }
#pragma unroll
    for (int nt = 0; nt < 4; ++nt) {
      int y = y0 + 4 * rg + nt;
      int x = x0 + ln;
      if (y < HWD && x < HWD) {
        us4 pk;
#pragma unroll
        for (int j = 0; j < 4; ++j)
          pk[j] = bf16_bits(fmaxf(acc[i][nt][j] * sc[j] + bi[j], 0.f));
        *reinterpret_cast<us4*>(outp + (((long long)b * HWD + y) * HWD + x) * 64 + ocb) = pk;
      }
    }
  }
#undef C1_LOAD
#undef C1_WRITE
}

// ---------------- fused conv2+conv3 per head ----------------
// tile: 8x16 output px. conv2 halo region 10x18 (computed per 32-oc half into
// s_buf, BN+ReLU, zeros at out-of-image = conv3 SAME padding), conv3 accumulates
// from s_buf. LDS: input 240px x 72sh (34.6KB) + buf 180px x 36sh (13KB) = 47.5KB
// -> 3 blocks/CU. grid 6912 = 6h x 4b x 24ty x 12tx (h innermost under swizzle).
__global__ __launch_bounds__(256, 3) void conv23_fused(
    const unsigned short* __restrict__ inp,   // shared NHWC bf16
    const unsigned short* __restrict__ w2b,   // [6][9][64][64]
    const unsigned short* __restrict__ w3b,   // [6][9][16][64]
    const float* __restrict__ bnH,            // [6][4][64]
    const float* __restrict__ b2,             // [6][3]
    float* __restrict__ hout) {               // head_out [B][12][H][W] f32
  __shared__ __align__(16) short s_in[240 * 72];
  __shared__ __align__(16) short s_buf[180 * 36];
  const int t = threadIdx.x;
  const int swz = xcd_swz(blockIdx.x, 6912);
  const int h = swz % 6;
  const int tile = swz / 6;
  const int b = tile / 288;
  const int tt = tile % 288;
  const int y0 = (tt / 12) * 8, x0 = (tt % 12) * 16;
  const int w = t >> 6, lane = t & 63, ln = lane & 15, kg = lane >> 4;

  // ---- stage input region 12x20 px x 64ch (rows y0-2.., cols x0-2..) ----
  for (int idx = t; idx < 1920; idx += 256) {
    int ch8 = idx & 7; int px = idx >> 3;
    int r = (px * 205) >> 12; int c = px - r * 20;
    int gy = y0 - 2 + r, gx = x0 - 2 + c;
    sh8 v = (sh8){0, 0, 0, 0, 0, 0, 0, 0};
    if (gy >= 0 && gy < HWD && gx >= 0 && gx < HWD)
      v = *reinterpret_cast<const sh8*>(
          &inp[(((long long)b * HWD + gy) * HWD + gx) * 64 + ch8 * 8]);
    *reinterpret_cast<sh8*>(&s_in[px * 72 + ch8 * 8]) = v;
  }

  // ---- per-lane conv2 N-geometry (3 Nt per wave over 10x18 region) ----
  int ibase[3];      // lds short-offset into s_in for tap (0,0)
  int qaddr[3];      // s_buf px index (clamped)
  bool wr_ok[3];     // q < 180
  bool img_ok[3];    // conv2 position inside image
#pragma unroll
  for (int nt = 0; nt < 3; ++nt) {
    int q = (w * 3 + nt) * 16 + ln;
    wr_ok[nt] = (q < 180);
    if (q > 179) q = 179;
    int r2 = (q * 57) >> 10; int c2 = q - r2 * 18;
    ibase[nt] = (r2 * 20 + c2) * 72 + kg * 8;
    qaddr[nt] = q;
    int gy2 = y0 - 1 + r2, gx2 = x0 - 1 + c2;
    img_ok[nt] = (gy2 >= 0 && gy2 < HWD && gx2 >= 0 && gx2 < HWD);
  }
  // ---- per-lane conv3 N-geometry (2 Nt per wave over 8x16 out tile) ----
  int b3base[2], oy[2], ox[2];
#pragma unroll
  for (int nt = 0; nt < 2; ++nt) {
    int p = (w * 2 + nt) * 16 + ln;
    int r3 = p >> 4, c3 = p & 15;
    b3base[nt] = ((r3 + 1) * 18 + (c3 + 1)) * 36 + kg * 8;
    oy[nt] = y0 + r3; ox[nt] = x0 + c3;
  }

  const float* bnp = bnH + h * 256;
  f4 acc3[2];
#pragma unroll
  for (int j = 0; j < 2; ++j) acc3[j] = (f4){0.f, 0.f, 0.f, 0.f};

  __syncthreads();

  for (int O = 0; O < 2; ++O) {
    // ---- conv2: 32-oc half over 10x18 region ----
    f4 acc2[2][3];
#pragma unroll
    for (int i = 0; i < 2; ++i)
#pragma unroll
      for (int j = 0; j < 3; ++j) acc2[i][j] = (f4){0.f, 0.f, 0.f, 0.f};
    for (int icq = 0; icq < 2; ++icq) {
#pragma unroll
      for (int tap = 0; tap < 9; ++tap) {
        const int ky = tap / 3, kx = tap % 3;
        const int toff = (ky * 20 + kx) * 72 + icq * 32;
        sh8 af[2];
#pragma unroll
        for (int mt = 0; mt < 2; ++mt)
          af[mt] = *reinterpret_cast<const sh8*>(
              w2b + (((h * 9 + tap) * 64) + O * 32 + mt * 16 + ln) * 64 + icq * 32 + kg * 8);
#pragma unroll
        for (int nt = 0; nt < 3; ++nt) {
          sh8 bf = *reinterpret_cast<const sh8*>(&s_in[ibase[nt] + toff]);
#pragma unroll
          for (int mt = 0; mt < 2; ++mt)
            acc2[mt][nt] = __builtin_amdgcn_mfma_f32_16x16x32_bf16(
                af[mt], bf, acc2[mt][nt], 0, 0, 0);
        }
      }
    }
    // ---- BN+ReLU -> s_buf (zeros outside image = conv3 SAME pad) ----
#pragma unroll
    for (int mt = 0; mt < 2; ++mt) {
      const int ocb = O * 32 + mt * 16 + kg * 4;
      f4 g4 = *reinterpret_cast<const f4*>(bnp + ocb);
      f4 b4 = *reinterpret_cast<const f4*>(bnp + 64 + ocb);
      f4 m4 = *reinterpret_cast<const f4*>(bnp + 128 + ocb);
      f4 v4 = *reinterpret_cast<const f4*>(bnp + 192 + ocb);
      f4 sc, bi;
#pragma unroll
      for (int j = 0; j < 4; ++j) {
        sc[j] = g4[j] * rsqrtf(v4[j] + 1e-5f);
        bi[j] = b4[j] - m4[j] * sc[j];
      }
#pragma unroll
      for (int nt = 0; nt < 3; ++nt) {
        if (wr_ok[nt]) {
          us4 pk = {0, 0, 0, 0};
          if (img_ok[nt]) {
#pragma unroll
            for (int j = 0; j < 4; ++j)
              pk[j] = bf16_bits(fmaxf(acc2[mt][nt][j] * sc[j] + bi[j], 0.f));
          }
          *reinterpret_cast<us4*>(&s_buf[qaddr[nt] * 36 + mt * 16 + kg * 4]) = pk;
        }
      }
    }
    __syncthreads();
    // ---- conv3: accumulate K=32 (this O half) ----
#pragma unroll
    for (int tap = 0; tap < 9; ++tap) {
      const int dy = tap / 3 - 1, dx = tap % 3 - 1;
      const int toff = (dy * 18 + dx) * 36;
      sh8 af3 = *reinterpret_cast<const sh8*>(
          w3b + (((h * 9 + tap) * 16) + ln) * 64 + O * 32 + kg * 8);
#pragma unroll
      for (int nt = 0; nt < 2; ++nt) {
        sh8 bf3 = *reinterpret_cast<const sh8*>(&s_buf[b3base[nt] + toff]);
        acc3[nt] = __builtin_amdgcn_mfma_f32_16x16x32_bf16(af3, bf3, acc3[nt], 0, 0, 0);
      }
    }
    __syncthreads();  // protect s_buf before next O overwrites
  }

  // ---- epilogue: + bias -> f32 NCHW head slices ----
  const int c_off = d_cum[h], noc = d_outc[h];
#pragma unroll
  for (int nt = 0; nt < 2; ++nt) {
    if (oy[nt] < HWD && ox[nt] < HWD) {
#pragma unroll
      for (int j = 0; j < 4; ++j) {
        int oc = kg * 4 + j;
        if (oc < noc)
          hout[((long long)b * 12 + c_off + oc) * NPX + oy[nt] * HWD + ox[nt]] =
              acc3[nt][j] + b2[h * 3 + oc];
      }
    }
  }
}

// ---------------- assign_targets: per-box ----------------
__global__ __launch_bounds__(256) void targets_kernel(
    const float* __restrict__ gt, float* __restrict__ out, float* __restrict__ boxp) {
  int idx = blockIdx.x * 256 + threadIdx.x;
  if (idx >= NB * NMAX) return;
  int b = idx / NMAX, j = idx - b * NMAX;
  float vals[8] = {0, 0, 0, 0, 0, 0, 0, 0};
  float indf = 0.f, mkf = 0.f;
  if (j < MBOX) {
    const float* g = gt + (b * MBOX + j) * 8;
    float x = g[0], y = g[1], z = g[2], dx = g[3], dy = g[4], dz = g[5];
    float hd = g[6], cls = g[7];
    float cx = (x - (-75.2f)) / 0.1f / 8.0f;
    cx = fminf(fmaxf(cx, 0.0f), (float)HWD - 0.5f);
    float cy = (y - (-75.2f)) / 0.1f / 8.0f;
    cy = fminf(fmaxf(cy, 0.0f), (float)HWD - 0.5f);
    float cxf = floorf(cx), cyf = floorf(cy);
    int cxi = (int)cxf, cyi = (int)cyf;
    float hh = dx / 0.1f / 8.0f;
    float ww = dy / 0.1f / 8.0f;
    const float ov = 0.1f;
    float b1 = hh + ww;
    float c1 = ww * hh * (1.0f - ov) / (1.0f + ov);
    float sq1 = sqrtf(fmaxf(b1 * b1 - 4.0f * c1, 0.0f));
    float r1 = (b1 + sq1) / 2.0f;
    float b2_ = 2.0f * (hh + ww);
    float c2 = (1.0f - ov) * ww * hh;
    float sq2 = sqrtf(fmaxf(b2_ * b2_ - 16.0f * c2, 0.0f));
    float r2 = (b2_ + sq2) / 2.0f;
    float a3 = 4.0f * ov;
    float b3 = -2.0f * ov * (hh + ww);
    float c3 = (ov - 1.0f) * ww * hh;
    float sq3 = sqrtf(fmaxf(b3 * b3 - 4.0f * a3 * c3, 0.0f));
    float r3 = (b3 + sq3) / 2.0f;
    float r = fminf(fminf(r1, r2), r3);
    r = fmaxf(floorf(r), 2.0f);
    float sigma = (2.0f * r + 1.0f) / 6.0f;
    float inv2s2 = 1.0f / (2.0f * sigma * sigma);
    bool valid = (dx > 0.0f) && (dy > 0.0f);
    float vf = valid ? 1.0f : 0.0f;
    vals[0] = (cx - cxf) * vf;
    vals[1] = (cy - cyf) * vf;
    vals[2] = z * vf;
    vals[3] = logf(dx) * vf;
    vals[4] = logf(dy) * vf;
    vals[5] = logf(dz) * vf;
    vals[6] = cosf(hd) * vf;
    vals[7] = sinf(hd) * vf;
    indf = (float)((cyi * HWD + cxi) * (valid ? 1 : 0));
    mkf = vf;
    float* bp = boxp + (b * MBOX + j) * 8;
    bp[0] = cxf; bp[1] = cyf; bp[2] = r; bp[3] = inv2s2;
    bp[4] = valid ? cls : 0.0f; bp[5] = 0.f; bp[6] = 0.f; bp[7] = 0.f;
  }
  float* tb = out + TB_OFF + (b * NMAX + j) * 8;
#pragma unroll
  for (int k = 0; k < 8; ++k) tb[k] = vals[k];
  out[IND_OFF + b * NMAX + j] = indf;
  out[MSK_OFF + b * NMAX + j] = mkf;
}

// ---------------- heatmap: per-pixel max over boxes ----------------
__global__ __launch_bounds__(256) void heatmap_kernel(
    const float* __restrict__ boxp, float* __restrict__ out) {
  __shared__ float s_bp[MBOX][5];
  const int t = threadIdx.x, b = blockIdx.y;
  for (int e = t; e < MBOX * 5; e += 256) {
    int j = e / 5, k = e - j * 5;
    s_bp[j][k] = boxp[(b * MBOX + j) * 8 + k];
  }
  __syncthreads();
  int p = blockIdx.x * 256 + t;
  if (p >= NPX) return;
  int y = p / HWD, x = p - y * HWD;
  float a0 = 0.f, a1 = 0.f, a2 = 0.f;
  for (int j = 0; j < MBOX; ++j) {
    int c = (int)s_bp[j][4];
    if (c == 0) continue;
    float ox = (float)x - s_bp[j][0];
    float oy = (float)y - s_bp[j][1];
    float r = s_bp[j][2];
    if (fabsf(ox) <= r && fabsf(oy) <= r) {
      float gg = expf(-(ox * ox + oy * oy) * s_bp[j][3]);
      if (c == 1) a0 = fmaxf(a0, gg);
      else if (c == 2) a1 = fmaxf(a1, gg);
      else a2 = fmaxf(a2, gg);
    }
  }
  int base = HM_OFF + (b * 3 * HWD + y) * HWD + x;
  out[base] = a0;
  out[base + NPX] = a1;
  out[base + 2 * NPX] = a2;
}

extern "C" void kernel_launch(void* const* d_in, const int* in_sizes, int n_in,
                              void* d_out, int out_size, void* d_ws, size_t ws_size,
                              hipStream_t stream) {
  (void)in_sizes; (void)n_in; (void)out_size; (void)ws_size;
  const float* sf = (const float*)d_in[0];
  const float* gt = (const float*)d_in[1];
  const float* w_shared = (const float*)d_in[2];
  const float* bn_shared = (const float*)d_in[3];
  const float* w1 = (const float*)d_in[4];
  const float* bnH = (const float*)d_in[5];
  const float* w2 = (const float*)d_in[6];
  const float* b2 = (const float*)d_in[7];
  float* out = (float*)d_out;
  char* ws = (char*)d_ws;

  // ws layout (bytes): shared (18.1MB) | w1b | w2b | w3b | boxp
  const size_t SH = (size_t)NB * NPX * 64 * 2;          // 18,096,128
  unsigned short* shared_t = (unsigned short*)ws;
  unsigned short* w1b = (unsigned short*)(ws + SH);                       // 589,824
  unsigned short* w2b = (unsigned short*)(ws + SH + 589824);              // 442,368
  unsigned short* w3b = (unsigned short*)(ws + SH + 589824 + 442368);     // 110,592
  float* boxp = (float*)(ws + SH + 589824 + 442368 + 110592);             // 25,600

  wprep<<<2232, 256, 0, stream>>>(w_shared, w1, w2, w1b, w2b, w3b);

  conv1_mfma<<<1152, 256, 0, stream>>>(sf, w1b, bn_shared, shared_t);

  conv23_fused<<<6912, 256, 0, stream>>>(shared_t, w2b, w3b, bnH, b2, out);

  targets_kernel<<<(NB * NMAX + 255) / 256, 256, 0, stream>>>(gt, out, boxp);
  heatmap_kernel<<<dim3((NPX + 255) / 256, NB), 256, 0, stream>>>(boxp, out);
}